// Round 1
// baseline (991.006 us; speedup 1.0000x reference)
//
#include <hip/hip_runtime.h>
#include <hip/hip_bf16.h>
#include <cstdint>
#include <cstddef>

// Problem constants
#define BDIM 8192
#define DDIM 1024
#define NCOL 16384          // 2*BDIM
#define TEMP_INV 20.0f      // 1/0.05

typedef __bf16 bf16;
typedef bf16 bf16x4 __attribute__((ext_vector_type(4)));
typedef bf16 bf16x8 __attribute__((ext_vector_type(8)));
typedef float f32x4 __attribute__((ext_vector_type(4)));

__device__ __forceinline__ void load_lds16(const void* g, void* l) {
    __builtin_amdgcn_global_load_lds(
        (const __attribute__((address_space(1))) void*)g,
        (__attribute__((address_space(3))) void*)l, 16, 0, 0);
}

// ---------------------------------------------------------------------------
// Kernel 1: L2-normalize each row of P/E/C (fp32 in) -> bf16 out in workspace.
// Also zeroes rowsum[8192] (ws is poisoned 0xAA before every launch).
// grid = 3*8192 blocks of 256 threads; one block per row.
// ---------------------------------------------------------------------------
__global__ __launch_bounds__(256) void norm_kernel(
    const float* __restrict__ P, const float* __restrict__ E,
    const float* __restrict__ C,
    bf16* __restrict__ Pb, bf16* __restrict__ Eb, bf16* __restrict__ Cb,
    float* __restrict__ rowsum)
{
    int b = blockIdx.x;
    int which = b >> 13;       // 0:P 1:E 2:C
    int row = b & (BDIM - 1);
    const float* src = (which == 0) ? P : (which == 1 ? E : C);
    bf16* dst = (which == 0) ? Pb : (which == 1 ? Eb : Cb);
    src += (size_t)row * DDIM;
    dst += (size_t)row * DDIM;

    int t = threadIdx.x;
    if (b < 32) rowsum[b * 256 + t] = 0.0f;   // zero the 8192-entry accumulator

    float4 v = ((const float4*)src)[t];       // 256 threads * 4 = 1024 elems
    float ss = v.x * v.x + v.y * v.y + v.z * v.z + v.w * v.w;
    #pragma unroll
    for (int m = 32; m >= 1; m >>= 1) ss += __shfl_xor(ss, m, 64);

    __shared__ float wsum[4];
    if ((t & 63) == 0) wsum[t >> 6] = ss;
    __syncthreads();
    float tot = wsum[0] + wsum[1] + wsum[2] + wsum[3];
    float inv = 1.0f / fmaxf(sqrtf(tot), 1e-8f);

    bf16x4 o;
    o[0] = (bf16)(v.x * inv);
    o[1] = (bf16)(v.y * inv);
    o[2] = (bf16)(v.z * inv);
    o[3] = (bf16)(v.w * inv);
    ((bf16x4*)dst)[t] = o;
}

// ---------------------------------------------------------------------------
// Kernel 2: bf16 GEMM (A * B^T) with fused scale + per-row sum(exp()).
// blockIdx.x = column tile (0..127 over 16384 cols; >=64 -> contra matrix)
// blockIdx.y = row tile (0..63). 256 threads = 4 waves, each wave 64x64.
// Tile 128x128, BK=32, one 16x16x32 MFMA per K-tile per (i,j) subtile.
// ---------------------------------------------------------------------------
__global__ __launch_bounds__(256) void gemm_kernel(
    const bf16* __restrict__ Pb, const bf16* __restrict__ Eb,
    const bf16* __restrict__ Cb,
    float* __restrict__ sims,        // d_out + 1 (float elems), row stride 16384
    float* __restrict__ rowsum)
{
    const int ct = blockIdx.x;
    const int rt = blockIdx.y;
    const bf16* Bsrc = (ct < 64) ? Eb : Cb;
    const int nb = (ct & 63) * 128;      // row offset into Bsrc
    const int mb = rt * 128;

    __shared__ bf16 As[128 * 32];
    __shared__ bf16 Bs[128 * 32];

    const int t = threadIdx.x;
    const int lane = t & 63;
    const int wave = t >> 6;
    const int wr = (wave >> 1) * 64;     // wave row offset in tile
    const int wc = (wave & 1) * 64;      // wave col offset in tile
    const int quad = lane >> 4;
    const int l15 = lane & 15;

    // staging: thread t loads 16B = 8 bf16; tile row t/4, col (t%4)*8; rows +0,+64
    const int srow = t >> 2;
    const int scol = (t & 3) * 8;
    const bf16* ga = Pb   + (size_t)(mb + srow) * DDIM + scol;
    const bf16* gb = Bsrc + (size_t)(nb + srow) * DDIM + scol;
    bf16* la = As + t * 8;               // byte offset t*16: wave-uniform base + lane*16
    bf16* lb = Bs + t * 8;

    f32x4 acc[4][4];
    #pragma unroll
    for (int i = 0; i < 4; i++)
        #pragma unroll
        for (int j = 0; j < 4; j++) {
            f32x4 z = {0.f, 0.f, 0.f, 0.f};
            acc[i][j] = z;
        }

    for (int kt = 0; kt < DDIM; kt += 32) {
        __syncthreads();   // prior iter's ds_reads done before overwrite
        load_lds16(ga + kt,                la);
        load_lds16(ga + kt + 64 * DDIM,    la + 64 * 32);
        load_lds16(gb + kt,                lb);
        load_lds16(gb + kt + 64 * DDIM,    lb + 64 * 32);
        __syncthreads();   // compiler drains vmcnt(0) before s_barrier

        // A frag: lane holds A[m=l15][k=quad*8+j]; B^T symmetry -> same layout
        bf16x8 af[4], bfr[4];
        #pragma unroll
        for (int i = 0; i < 4; i++)
            af[i] = *(const bf16x8*)(As + (wr + i * 16 + l15) * 32 + quad * 8);
        #pragma unroll
        for (int j = 0; j < 4; j++)
            bfr[j] = *(const bf16x8*)(Bs + (wc + j * 16 + l15) * 32 + quad * 8);

        #pragma unroll
        for (int i = 0; i < 4; i++)
            #pragma unroll
            for (int j = 0; j < 4; j++)
                acc[i][j] = __builtin_amdgcn_mfma_f32_16x16x32_bf16(
                    af[i], bfr[j], acc[i][j], 0, 0, 0);
    }

    // Epilogue: C/D layout col = lane&15, row = quad*4 + reg.
    // Scale by 1/TEMP, store scalar (sims base is 4B-misaligned vs 16B),
    // and accumulate per-row sum(exp(.)) -> atomicAdd into rowsum.
    const int gcolbase = ct * 128 + wc + l15;
    #pragma unroll
    for (int i = 0; i < 4; i++) {
        #pragma unroll
        for (int r = 0; r < 4; r++) {
            const int grow = mb + wr + i * 16 + quad * 4 + r;
            float* orow = sims + (size_t)grow * NCOL;
            float rs = 0.f;
            #pragma unroll
            for (int j = 0; j < 4; j++) {
                float v = acc[i][j][r] * TEMP_INV;
                orow[gcolbase + j * 16] = v;
                rs += __expf(v);
            }
            // reduce over the 16 lanes of this quad (distinct columns)
            rs += __shfl_xor(rs, 1, 64);
            rs += __shfl_xor(rs, 2, 64);
            rs += __shfl_xor(rs, 4, 64);
            rs += __shfl_xor(rs, 8, 64);
            if (l15 == 0) atomicAdd(&rowsum[grow], rs);
        }
    }
}

// ---------------------------------------------------------------------------
// Kernel 3: loss = mean_i( log(rowsum[i]) - sims[i][i] )  -> d_out[0]
// ---------------------------------------------------------------------------
__global__ __launch_bounds__(1024) void finalize_kernel(
    const float* __restrict__ rowsum, const float* __restrict__ sims,
    float* __restrict__ out)
{
    int t = threadIdx.x;
    float s = 0.f;
    for (int i = t; i < BDIM; i += 1024) {
        float logz = logf(rowsum[i]);
        float tgt = sims[(size_t)i * NCOL + i];
        s += logz - tgt;
    }
    #pragma unroll
    for (int m = 32; m >= 1; m >>= 1) s += __shfl_xor(s, m, 64);
    __shared__ float ws[16];
    if ((t & 63) == 0) ws[t >> 6] = s;
    __syncthreads();
    if (t == 0) {
        float tot = 0.f;
        #pragma unroll
        for (int k = 0; k < 16; k++) tot += ws[k];
        out[0] = tot / (float)BDIM;
    }
}

// ---------------------------------------------------------------------------
extern "C" void kernel_launch(void* const* d_in, const int* in_sizes, int n_in,
                              void* d_out, int out_size, void* d_ws, size_t ws_size,
                              hipStream_t stream) {
    const float* P = (const float*)d_in[0];
    const float* E = (const float*)d_in[1];
    const float* C = (const float*)d_in[2];
    float* out = (float*)d_out;
    float* sims = out + 1;   // output 0 = loss scalar, then sims [8192,16384]

    constexpr size_t MAT_BYTES = (size_t)BDIM * DDIM * sizeof(bf16);  // 16 MB
    uint8_t* ws = (uint8_t*)d_ws;
    bf16* Pb = (bf16*)(ws);
    bf16* Eb = (bf16*)(ws + MAT_BYTES);
    bf16* Cb = (bf16*)(ws + 2 * MAT_BYTES);
    float* rowsum = (float*)(ws + 3 * MAT_BYTES);   // 8192 floats

    norm_kernel<<<3 * BDIM, 256, 0, stream>>>(P, E, C, Pb, Eb, Cb, rowsum);
    dim3 grid(128, 64);
    gemm_kernel<<<grid, 256, 0, stream>>>(Pb, Eb, Cb, sims, rowsum);
    finalize_kernel<<<1, 1024, 0, stream>>>(rowsum, sims, out);
}